// Round 1
// baseline (428.232 us; speedup 1.0000x reference)
//
#include <hip/hip_runtime.h>

// RandomizedNodeLabeling: graph signature features.
//   N = 100000 nodes, D = 64 dims, NADJ = 1.6M sorted-row COO edges, E = 262144 query edges.
// Pipeline:
//   1. xw = x * node_weight[:,None]
//   2. row_ptr from sorted adj_row (binary search per node)
//   3. one_hop[r] = sum_{e in row r} xw[adj_col[e]];  deg[r] = degree
//   4. two_iter[r] = sum xw_one_hop[adj_col[e]];  deg2[r] = max(sum deg[col] - deg[r] - 1, 0)
//   5. per query edge: 9 wave-reduced dot products -> 15 features

#define D 64

__device__ __forceinline__ float wave_sum(float v) {
    // butterfly over full 64-lane wave; all lanes end with the sum
    v += __shfl_xor(v, 32, 64);
    v += __shfl_xor(v, 16, 64);
    v += __shfl_xor(v, 8, 64);
    v += __shfl_xor(v, 4, 64);
    v += __shfl_xor(v, 2, 64);
    v += __shfl_xor(v, 1, 64);
    return v;
}

__global__ void __launch_bounds__(256) xw_kernel(const float* __restrict__ x,
                                                 const float* __restrict__ w,
                                                 float* __restrict__ xw, int n) {
    int i = blockIdx.x * blockDim.x + threadIdx.x;   // over n*16 float4 groups
    if (i >= n * (D / 4)) return;
    int node = i / (D / 4);
    float4 v = ((const float4*)x)[i];
    float s = w[node];
    v.x *= s; v.y *= s; v.z *= s; v.w *= s;
    ((float4*)xw)[i] = v;
}

__global__ void __launch_bounds__(256) row_ptr_kernel(const int* __restrict__ adj_row,
                                                      int* __restrict__ row_ptr,
                                                      int n, int nadj) {
    int i = blockIdx.x * blockDim.x + threadIdx.x;
    if (i > n) return;
    int lo = 0, hi = nadj;                 // lower_bound(adj_row, i)
    while (lo < hi) {
        int mid = (lo + hi) >> 1;
        if (adj_row[mid] < i) lo = mid + 1; else hi = mid;
    }
    row_ptr[i] = lo;
}

// one wave per node, lane = dim. dst[r] = sum_{e} src[adj_col[e]]; deg[r] = degree.
__global__ void __launch_bounds__(256) spmm1_kernel(const float* __restrict__ src,
                                                    const int* __restrict__ row_ptr,
                                                    const int* __restrict__ adj_col,
                                                    float* __restrict__ dst,
                                                    float* __restrict__ deg,
                                                    int n) {
    int node = blockIdx.x * 4 + (threadIdx.x >> 6);
    int lane = threadIdx.x & 63;
    if (node >= n) return;
    int start = row_ptr[node], end = row_ptr[node + 1];
    float acc0 = 0.f, acc1 = 0.f;
    int e = start;
    for (; e + 1 < end; e += 2) {          // 2 independent gathers in flight
        int c0 = adj_col[e], c1 = adj_col[e + 1];
        acc0 += src[(size_t)c0 * D + lane];
        acc1 += src[(size_t)c1 * D + lane];
    }
    if (e < end) acc0 += src[(size_t)adj_col[e] * D + lane];
    dst[(size_t)node * D + lane] = acc0 + acc1;
    if (lane == 0) deg[node] = (float)(end - start);
}

// second hop: also accumulates sum of neighbor degrees -> deg2
__global__ void __launch_bounds__(256) spmm2_kernel(const float* __restrict__ src,
                                                    const int* __restrict__ row_ptr,
                                                    const int* __restrict__ adj_col,
                                                    const float* __restrict__ deg,
                                                    float* __restrict__ dst,
                                                    float* __restrict__ deg2,
                                                    int n) {
    int node = blockIdx.x * 4 + (threadIdx.x >> 6);
    int lane = threadIdx.x & 63;
    if (node >= n) return;
    int start = row_ptr[node], end = row_ptr[node + 1];
    float acc0 = 0.f, acc1 = 0.f, dsum = 0.f;
    int e = start;
    for (; e + 1 < end; e += 2) {
        int c0 = adj_col[e], c1 = adj_col[e + 1];
        acc0 += src[(size_t)c0 * D + lane];
        acc1 += src[(size_t)c1 * D + lane];
        dsum += deg[c0] + deg[c1];         // broadcast loads, L2-hit
    }
    if (e < end) {
        int c = adj_col[e];
        acc0 += src[(size_t)c * D + lane];
        dsum += deg[c];
    }
    dst[(size_t)node * D + lane] = acc0 + acc1;
    if (lane == 0) {
        float dg = (float)(end - start);
        deg2[node] = fmaxf(dsum - dg - 1.0f, 0.0f);
    }
}

// one wave per query edge; 9 dot products over D=64 via butterfly reduction
__global__ void __launch_bounds__(256) edge_kernel(const int* __restrict__ edges, // [2,E]
                                                   const float* __restrict__ xw,
                                                   const float* __restrict__ h1,
                                                   const float* __restrict__ t2,
                                                   const float* __restrict__ deg,
                                                   const float* __restrict__ deg2,
                                                   float* __restrict__ out,
                                                   int E) {
    int q = blockIdx.x * 4 + (threadIdx.x >> 6);
    int lane = threadIdx.x & 63;
    if (q >= E) return;
    int u = edges[q];
    int v = edges[E + q];
    size_t ub = (size_t)u * D + lane, vb = (size_t)v * D + lane;
    float xwu = xw[ub], xwv = xw[vb];
    float h1u = h1[ub], h1v = h1[vb];
    float tu  = t2[ub], tv  = t2[vb];
    float du  = deg[u],  dv  = deg[v];
    float du2 = deg2[u], dv2 = deg2[v];

    float h2u = tu - h1u - xwu;
    float h2v = tv - h1v - xwv;
    float au  = tu - du * xwu;
    float av  = tv - dv * xwv;

    float c11  = wave_sum(h1u * h1v);
    float c12  = wave_sum(h1u * h2v);
    float c21  = wave_sum(h2u * h1v);
    float c22  = wave_sum(h2u * h2v);
    float cc12 = wave_sum(h1u * tv);
    float cc21 = wave_sum(tu * h1v);
    float cc22 = wave_sum(au * av);
    float cs12 = wave_sum(h1u * tu);
    float cs21 = wave_sum(h1v * tv);

    if (lane == 0) {
        float* o = out + (size_t)q * 15;
        o[0]  = c11;
        o[1]  = c12;
        o[2]  = c21;
        o[3]  = c22;
        o[4]  = du + dv - 2.f * c11 - c12 - c21;
        o[5]  = du2 + dv2 - 2.f * c22 - c12 - c21;
        o[6]  = cc12;
        o[7]  = cc21;
        o[8]  = cc22;
        o[9]  = cs12;
        o[10] = cs21;
        o[11] = du;
        o[12] = dv;
        o[13] = du2;
        o[14] = dv2;
    }
}

extern "C" void kernel_launch(void* const* d_in, const int* in_sizes, int n_in,
                              void* d_out, int out_size, void* d_ws, size_t ws_size,
                              hipStream_t stream) {
    const float* x       = (const float*)d_in[0];
    const float* w       = (const float*)d_in[1];
    const int*   edges   = (const int*)d_in[2];
    const int*   adj_row = (const int*)d_in[3];
    const int*   adj_col = (const int*)d_in[4];

    const int N    = in_sizes[1];        // node_weight length
    const int E    = in_sizes[2] / 2;
    const int NADJ = in_sizes[3];

    // workspace layout (256B-aligned)
    char* ws = (char*)d_ws;
    size_t off = 0;
    auto take = [&](size_t bytes) {
        void* p = ws + off;
        off = (off + bytes + 255) & ~(size_t)255;
        return p;
    };
    float* xw      = (float*)take((size_t)N * D * sizeof(float));
    float* one_hop = (float*)take((size_t)N * D * sizeof(float));
    float* two_it  = (float*)take((size_t)N * D * sizeof(float));
    float* deg     = (float*)take((size_t)N * sizeof(float));
    float* deg2    = (float*)take((size_t)N * sizeof(float));
    int*   row_ptr = (int*)take((size_t)(N + 1) * sizeof(int));
    (void)ws_size;

    float* out = (float*)d_out;

    // 1. xw
    {
        int total = N * (D / 4);
        xw_kernel<<<(total + 255) / 256, 256, 0, stream>>>(x, w, xw, N);
    }
    // 2. CSR row pointers from sorted adj_row
    row_ptr_kernel<<<(N + 1 + 255) / 256, 256, 0, stream>>>(adj_row, row_ptr, N, NADJ);
    // 3. one_hop + deg
    spmm1_kernel<<<(N + 3) / 4, 256, 0, stream>>>(xw, row_ptr, adj_col, one_hop, deg, N);
    // 4. two_iter + deg2
    spmm2_kernel<<<(N + 3) / 4, 256, 0, stream>>>(one_hop, row_ptr, adj_col, deg, two_it, deg2, N);
    // 5. edge features
    edge_kernel<<<(E + 3) / 4, 256, 0, stream>>>(edges, xw, one_hop, two_it, deg, deg2, out, E);
}

// Round 2
// 215.448 us; speedup vs baseline: 1.9876x; 1.9876x over previous
//
#include <hip/hip_runtime.h>

// RandomizedNodeLabeling — bf16-compressed node-vector tables + wide gathers.
// N=100000 nodes, D=64, NADJ=1.6M sorted-row COO, E=262144 query edges.
//
// Node vector = 64 bf16 = 128 B = 8 x uint4. Lane sub (0..7) owns dims
// sub*8 .. sub*8+7 (each uint = 2 bf16, lo = even dim).
//
// spmm: one wave per node; 8 slots x 8 lanes -> 8 edges gathered per load
//       instruction (1 KB in flight), fp32 accumulate, slot-reduce via
//       shfl_xor(8,16,32), bf16 store by slot 0.
// edge: 8 lanes per edge, 8 edges per wave; 6 x 1KB gather loads, 9 dots
//       in fp32, group-reduce via shfl_xor(1,2,4).

#define D 64

typedef unsigned int uint32;

__device__ __forceinline__ uint32 pack2(float a, float b) {
    // round-to-nearest-even bf16 pack: a -> lo16, b -> hi16
    uint32 ua = __float_as_uint(a);
    ua += 0x7fffu + ((ua >> 16) & 1u);
    uint32 ub = __float_as_uint(b);
    ub += 0x7fffu + ((ub >> 16) & 1u);
    return (ua >> 16) | (ub & 0xffff0000u);
}
__device__ __forceinline__ float lo2f(uint32 u) { return __uint_as_float(u << 16); }
__device__ __forceinline__ float hi2f(uint32 u) { return __uint_as_float(u & 0xffff0000u); }

#define RED_SLOT(v) { v += __shfl_xor(v, 8, 64); v += __shfl_xor(v, 16, 64); v += __shfl_xor(v, 32, 64); }
#define RED_GRP(v)  { v += __shfl_xor(v, 1, 64); v += __shfl_xor(v, 2, 64);  v += __shfl_xor(v, 4, 64);  }

__global__ void __launch_bounds__(256) xw_kernel(const float4* __restrict__ x,
                                                 const float* __restrict__ w,
                                                 uint4* __restrict__ xw, int n8) {
    int i = blockIdx.x * blockDim.x + threadIdx.x;   // over n*8 uint4 groups
    if (i >= n8) return;
    float s = w[i >> 3];
    float4 a = x[i * 2], b = x[i * 2 + 1];
    uint4 o;
    o.x = pack2(a.x * s, a.y * s);
    o.y = pack2(a.z * s, a.w * s);
    o.z = pack2(b.x * s, b.y * s);
    o.w = pack2(b.z * s, b.w * s);
    xw[i] = o;
}

__global__ void __launch_bounds__(256) row_ptr_kernel(const int* __restrict__ adj_row,
                                                      int* __restrict__ row_ptr,
                                                      int n, int nadj) {
    int i = blockIdx.x * blockDim.x + threadIdx.x;
    if (i > n) return;
    int lo = 0, hi = nadj;                 // lower_bound(adj_row, i)
    while (lo < hi) {
        int mid = (lo + hi) >> 1;
        if (adj_row[mid] < i) lo = mid + 1; else hi = mid;
    }
    row_ptr[i] = lo;
}

// WITH_DEG2=false: dst = A*src (bf16), degout = degree
// WITH_DEG2=true : dst = A*src (bf16), degout = max(A*degin - deg - 1, 0)
template <bool WITH_DEG2>
__global__ void __launch_bounds__(256) spmm_kernel(const uint4* __restrict__ src,
                                                   const int* __restrict__ row_ptr,
                                                   const int* __restrict__ adj_col,
                                                   const float* __restrict__ degin,
                                                   uint4* __restrict__ dst,
                                                   float* __restrict__ degout,
                                                   int n) {
    int node = blockIdx.x * 4 + (threadIdx.x >> 6);
    int lane = threadIdx.x & 63;
    int slot = lane >> 3, sub = lane & 7;
    if (node >= n) return;
    int start = row_ptr[node], end = row_ptr[node + 1];
    float a0 = 0.f, a1 = 0.f, a2 = 0.f, a3 = 0.f,
          a4 = 0.f, a5 = 0.f, a6 = 0.f, a7 = 0.f;
    float dsum = 0.f;
    for (int base = start; base < end; base += 8) {
        int e = base + slot;
        bool valid = e < end;
        int ec = valid ? e : end - 1;      // clamp (end > start here)
        int c = adj_col[ec];
        uint4 qv = src[c * 8 + sub];
        if (!valid) { qv.x = 0u; qv.y = 0u; qv.z = 0u; qv.w = 0u; }
        a0 += lo2f(qv.x); a1 += hi2f(qv.x);
        a2 += lo2f(qv.y); a3 += hi2f(qv.y);
        a4 += lo2f(qv.z); a5 += hi2f(qv.z);
        a6 += lo2f(qv.w); a7 += hi2f(qv.w);
        if (WITH_DEG2) dsum += valid ? degin[c] : 0.f;
    }
    // sum across the 8 slots (xor distances 8,16,32); dims stay per-sub
    RED_SLOT(a0) RED_SLOT(a1) RED_SLOT(a2) RED_SLOT(a3)
    RED_SLOT(a4) RED_SLOT(a5) RED_SLOT(a6) RED_SLOT(a7)
    if (WITH_DEG2) RED_SLOT(dsum)
    if (slot == 0) {
        uint4 o;
        o.x = pack2(a0, a1); o.y = pack2(a2, a3);
        o.z = pack2(a4, a5); o.w = pack2(a6, a7);
        dst[node * 8 + sub] = o;
    }
    if (lane == 0) {
        float dg = (float)(end - start);
        if (WITH_DEG2) degout[node] = fmaxf(dsum - dg - 1.0f, 0.0f);
        else           degout[node] = dg;
    }
}

__global__ void __launch_bounds__(256) edge_kernel(const int* __restrict__ edges, // [2,E]
                                                   const uint4* __restrict__ xw,
                                                   const uint4* __restrict__ h1,
                                                   const uint4* __restrict__ t2,
                                                   const float* __restrict__ deg,
                                                   const float* __restrict__ deg2,
                                                   float* __restrict__ out,
                                                   int E) {
    int t = blockIdx.x * blockDim.x + threadIdx.x;
    int q = t >> 3, sub = t & 7;           // 8 lanes per edge
    if (q >= E) return;
    int u = edges[q], v = edges[E + q];
    uint4 pxu = xw[u * 8 + sub], pxv = xw[v * 8 + sub];
    uint4 phu = h1[u * 8 + sub], phv = h1[v * 8 + sub];
    uint4 ptu = t2[u * 8 + sub], ptv = t2[v * 8 + sub];
    float du = deg[u], dv = deg[v];

    float c11 = 0.f, c12 = 0.f, c21 = 0.f, c22 = 0.f,
          cc12 = 0.f, cc21 = 0.f, cc22 = 0.f, cs12 = 0.f, cs21 = 0.f;

    uint32 axu[4] = {pxu.x, pxu.y, pxu.z, pxu.w};
    uint32 axv[4] = {pxv.x, pxv.y, pxv.z, pxv.w};
    uint32 ahu[4] = {phu.x, phu.y, phu.z, phu.w};
    uint32 ahv[4] = {phv.x, phv.y, phv.z, phv.w};
    uint32 atu[4] = {ptu.x, ptu.y, ptu.z, ptu.w};
    uint32 atv[4] = {ptv.x, ptv.y, ptv.z, ptv.w};

    auto accum = [&](float xu, float xv, float hu, float hv, float tu, float tv) {
        float h2u = tu - hu - xu, h2v = tv - hv - xv;
        float au = fmaf(-du, xu, tu), av = fmaf(-dv, xv, tv);
        c11  = fmaf(hu,  hv,  c11);
        c12  = fmaf(hu,  h2v, c12);
        c21  = fmaf(h2u, hv,  c21);
        c22  = fmaf(h2u, h2v, c22);
        cc12 = fmaf(hu,  tv,  cc12);
        cc21 = fmaf(tu,  hv,  cc21);
        cc22 = fmaf(au,  av,  cc22);
        cs12 = fmaf(hu,  tu,  cs12);
        cs21 = fmaf(hv,  tv,  cs21);
    };
#pragma unroll
    for (int k = 0; k < 4; ++k) {
        accum(lo2f(axu[k]), lo2f(axv[k]), lo2f(ahu[k]), lo2f(ahv[k]), lo2f(atu[k]), lo2f(atv[k]));
        accum(hi2f(axu[k]), hi2f(axv[k]), hi2f(ahu[k]), hi2f(ahv[k]), hi2f(atu[k]), hi2f(atv[k]));
    }
    // reduce across the 8 lanes of this edge's group
    RED_GRP(c11) RED_GRP(c12) RED_GRP(c21) RED_GRP(c22)
    RED_GRP(cc12) RED_GRP(cc21) RED_GRP(cc22) RED_GRP(cs12) RED_GRP(cs21)

    if (sub == 0) {
        float du2 = deg2[u], dv2 = deg2[v];
        float* o = out + (size_t)q * 15;
        o[0]  = c11;
        o[1]  = c12;
        o[2]  = c21;
        o[3]  = c22;
        o[4]  = du + dv - 2.f * c11 - c12 - c21;
        o[5]  = du2 + dv2 - 2.f * c22 - c12 - c21;
        o[6]  = cc12;
        o[7]  = cc21;
        o[8]  = cc22;
        o[9]  = cs12;
        o[10] = cs21;
        o[11] = du;
        o[12] = dv;
        o[13] = du2;
        o[14] = dv2;
    }
}

extern "C" void kernel_launch(void* const* d_in, const int* in_sizes, int n_in,
                              void* d_out, int out_size, void* d_ws, size_t ws_size,
                              hipStream_t stream) {
    const float* x       = (const float*)d_in[0];
    const float* w       = (const float*)d_in[1];
    const int*   edges   = (const int*)d_in[2];
    const int*   adj_row = (const int*)d_in[3];
    const int*   adj_col = (const int*)d_in[4];

    const int N    = in_sizes[1];        // node_weight length
    const int E    = in_sizes[2] / 2;
    const int NADJ = in_sizes[3];

    char* ws = (char*)d_ws;
    size_t off = 0;
    auto take = [&](size_t bytes) {
        void* p = ws + off;
        off = (off + bytes + 255) & ~(size_t)255;
        return p;
    };
    uint4* xw      = (uint4*)take((size_t)N * D * 2);   // bf16 tables, 128 B/node
    uint4* one_hop = (uint4*)take((size_t)N * D * 2);
    uint4* two_it  = (uint4*)take((size_t)N * D * 2);
    float* deg     = (float*)take((size_t)N * sizeof(float));
    float* deg2    = (float*)take((size_t)N * sizeof(float));
    int*   row_ptr = (int*)take((size_t)(N + 1) * sizeof(int));
    (void)ws_size;

    float* out = (float*)d_out;

    {   // 1. xw (bf16)
        int n8 = N * 8;
        xw_kernel<<<(n8 + 255) / 256, 256, 0, stream>>>((const float4*)x, w, xw, n8);
    }
    // 2. CSR row pointers from sorted adj_row
    row_ptr_kernel<<<(N + 1 + 255) / 256, 256, 0, stream>>>(adj_row, row_ptr, N, NADJ);
    // 3. one_hop + deg
    spmm_kernel<false><<<(N + 3) / 4, 256, 0, stream>>>(xw, row_ptr, adj_col, nullptr,
                                                        one_hop, deg, N);
    // 4. two_iter + deg2
    spmm_kernel<true><<<(N + 3) / 4, 256, 0, stream>>>(one_hop, row_ptr, adj_col, deg,
                                                       two_it, deg2, N);
    // 5. edge features
    edge_kernel<<<((size_t)E * 8 + 255) / 256, 256, 0, stream>>>(edges, xw, one_hop, two_it,
                                                                 deg, deg2, out, E);
}

// Round 4
// 215.253 us; speedup vs baseline: 1.9894x; 1.0009x over previous
//
#include <hip/hip_runtime.h>

// RandomizedNodeLabeling — bf16 node-vector bundle + wide, dependency-free gathers.
// N=100000 nodes, D=64, NADJ=1.6M sorted-row COO, E=262144 query edges.
//
// Node bundle = 24 x uint4 (384 B): [0..7]=xw, [8..15]=one_hop, [16..23]=two_iter,
// each 64 bf16 (lane sub 0..7 owns dims sub*8..sub*8+7, lo=even dim).
// degpair[n] = {deg, deg2} (float2).
//
// spmm: one wave per node. Preload <=64 col indices in ONE coalesced load,
//       broadcast via shfl -> vector gathers have no load->load dependency.
//       8 slots x 8 lanes: each gather instr covers 8 edges (1 KB in flight).
//       Tail slots exec-masked (no wasted bandwidth).
// edge: 8 lanes per edge, 6 contiguous-uint4 gathers per endpoint from the
//       bundle (one 384 B block), 9 fp32 dots, shfl_xor(1,2,4) reduce.

#define D 64
#define BSTRIDE 24   // uint4 per node bundle
#define XW_OFF 0
#define H1_OFF 8
#define T2_OFF 16

typedef unsigned int uint32;

__device__ __forceinline__ uint32 pack2(float a, float b) {
    // round-to-nearest-even bf16 pack: a -> lo16, b -> hi16
    uint32 ua = __float_as_uint(a);
    ua += 0x7fffu + ((ua >> 16) & 1u);
    uint32 ub = __float_as_uint(b);
    ub += 0x7fffu + ((ub >> 16) & 1u);
    return (ua >> 16) | (ub & 0xffff0000u);
}
__device__ __forceinline__ float lo2f(uint32 u) { return __uint_as_float(u << 16); }
__device__ __forceinline__ float hi2f(uint32 u) { return __uint_as_float(u & 0xffff0000u); }

#define RED_SLOT(v) { v += __shfl_xor(v, 8, 64); v += __shfl_xor(v, 16, 64); v += __shfl_xor(v, 32, 64); }
#define RED_GRP(v)  { v += __shfl_xor(v, 1, 64); v += __shfl_xor(v, 2, 64);  v += __shfl_xor(v, 4, 64);  }
#define RED_ALL(v)  { RED_GRP(v) RED_SLOT(v) }

__global__ void __launch_bounds__(256) xw_kernel(const float4* __restrict__ x,
                                                 const float* __restrict__ w,
                                                 uint4* __restrict__ bundle, int n8) {
    int i = blockIdx.x * blockDim.x + threadIdx.x;   // over n*8 uint4 groups
    if (i >= n8) return;
    int node = i >> 3, sub = i & 7;
    float s = w[node];
    float4 a = x[i * 2], b = x[i * 2 + 1];
    uint4 o;
    o.x = pack2(a.x * s, a.y * s);
    o.y = pack2(a.z * s, a.w * s);
    o.z = pack2(b.x * s, b.y * s);
    o.w = pack2(b.z * s, b.w * s);
    bundle[(size_t)node * BSTRIDE + XW_OFF + sub] = o;
}

__global__ void __launch_bounds__(256) row_ptr_kernel(const int* __restrict__ adj_row,
                                                      int* __restrict__ row_ptr,
                                                      int n, int nadj) {
    int i = blockIdx.x * blockDim.x + threadIdx.x;
    if (i > n) return;
    int lo = 0, hi = nadj;                 // lower_bound(adj_row, i)
    while (lo < hi) {
        int mid = (lo + hi) >> 1;
        if (adj_row[mid] < i) lo = mid + 1; else hi = mid;
    }
    row_ptr[i] = lo;
}

// dst = A*src (bf16 in bundle layout). src/dst pre-offset by caller.
// WITH_DEG2=false: degpair[node].x = degree
// WITH_DEG2=true : degpair[node].y = max(sum_deg_of_neighbors - deg - 1, 0)
template <bool WITH_DEG2>
__global__ void __launch_bounds__(256) spmm_kernel(const uint4* __restrict__ src,
                                                   const int* __restrict__ row_ptr,
                                                   const int* __restrict__ adj_col,
                                                   float2* __restrict__ degpair,
                                                   uint4* __restrict__ dst,
                                                   int n) {
    int node = blockIdx.x * 4 + (threadIdx.x >> 6);
    int lane = threadIdx.x & 63;
    int slot = lane >> 3, sub = lane & 7;
    if (node >= n) return;
    int start = row_ptr[node], end = row_ptr[node + 1];
    int deg_n = end - start;
    float a0 = 0.f, a1 = 0.f, a2 = 0.f, a3 = 0.f,
          a4 = 0.f, a5 = 0.f, a6 = 0.f, a7 = 0.f;
    float dsum = 0.f;
    for (int base = 0; base < deg_n; base += 64) {
        int cnt = deg_n - base; if (cnt > 64) cnt = 64;
        // one coalesced load of up to 64 col indices for this node
        int myc = adj_col[start + base + (lane < cnt ? lane : cnt - 1)];
        if (WITH_DEG2) {
            if (lane < cnt) dsum += degpair[myc].x;   // L2-resident 800 KB table
        }
        for (int off = 0; off < cnt; off += 8) {
            int e = off + slot;
            int c = __shfl(myc, e, 64);               // broadcast, no mem dep
            if (e < cnt) {                            // exec-masked tail
                uint4 qv = src[(size_t)c * BSTRIDE + sub];
                a0 += lo2f(qv.x); a1 += hi2f(qv.x);
                a2 += lo2f(qv.y); a3 += hi2f(qv.y);
                a4 += lo2f(qv.z); a5 += hi2f(qv.z);
                a6 += lo2f(qv.w); a7 += hi2f(qv.w);
            }
        }
    }
    // sum across the 8 slots (xor distances 8,16,32); dims stay per-sub
    RED_SLOT(a0) RED_SLOT(a1) RED_SLOT(a2) RED_SLOT(a3)
    RED_SLOT(a4) RED_SLOT(a5) RED_SLOT(a6) RED_SLOT(a7)
    if (WITH_DEG2) RED_ALL(dsum)
    if (slot == 0) {
        uint4 o;
        o.x = pack2(a0, a1); o.y = pack2(a2, a3);
        o.z = pack2(a4, a5); o.w = pack2(a6, a7);
        dst[(size_t)node * BSTRIDE + sub] = o;
    }
    if (lane == 0) {
        float* dp = (float*)&degpair[node];
        if (WITH_DEG2) dp[1] = fmaxf(dsum - (float)deg_n - 1.0f, 0.0f);
        else           dp[0] = (float)deg_n;
    }
}

__global__ void __launch_bounds__(256) edge_kernel(const int* __restrict__ edges, // [2,E]
                                                   const uint4* __restrict__ bundle,
                                                   const float2* __restrict__ degpair,
                                                   float* __restrict__ out,
                                                   int E) {
    int t = blockIdx.x * blockDim.x + threadIdx.x;
    int q = t >> 3, sub = t & 7;           // 8 lanes per edge
    if (q >= E) return;
    int u = edges[q], v = edges[E + q];
    const uint4* bu = bundle + (size_t)u * BSTRIDE;
    const uint4* bv = bundle + (size_t)v * BSTRIDE;
    uint4 pxu = bu[XW_OFF + sub], phu = bu[H1_OFF + sub], ptu = bu[T2_OFF + sub];
    uint4 pxv = bv[XW_OFF + sub], phv = bv[H1_OFF + sub], ptv = bv[T2_OFF + sub];
    float2 dpu = degpair[u], dpv = degpair[v];
    float du = dpu.x, du2 = dpu.y, dv = dpv.x, dv2 = dpv.y;

    float c11 = 0.f, c12 = 0.f, c21 = 0.f, c22 = 0.f,
          cc12 = 0.f, cc21 = 0.f, cc22 = 0.f, cs12 = 0.f, cs21 = 0.f;

    uint32 axu[4] = {pxu.x, pxu.y, pxu.z, pxu.w};
    uint32 axv[4] = {pxv.x, pxv.y, pxv.z, pxv.w};
    uint32 ahu[4] = {phu.x, phu.y, phu.z, phu.w};
    uint32 ahv[4] = {phv.x, phv.y, phv.z, phv.w};
    uint32 atu[4] = {ptu.x, ptu.y, ptu.z, ptu.w};
    uint32 atv[4] = {ptv.x, ptv.y, ptv.z, ptv.w};

    auto accum = [&](float xu, float xv, float hu, float hv, float tu, float tv) {
        float h2u = tu - hu - xu, h2v = tv - hv - xv;
        float au = fmaf(-du, xu, tu), av = fmaf(-dv, xv, tv);
        c11  = fmaf(hu,  hv,  c11);
        c12  = fmaf(hu,  h2v, c12);
        c21  = fmaf(h2u, hv,  c21);
        c22  = fmaf(h2u, h2v, c22);
        cc12 = fmaf(hu,  tv,  cc12);
        cc21 = fmaf(tu,  hv,  cc21);
        cc22 = fmaf(au,  av,  cc22);
        cs12 = fmaf(hu,  tu,  cs12);
        cs21 = fmaf(hv,  tv,  cs21);
    };
#pragma unroll
    for (int k = 0; k < 4; ++k) {
        accum(lo2f(axu[k]), lo2f(axv[k]), lo2f(ahu[k]), lo2f(ahv[k]), lo2f(atu[k]), lo2f(atv[k]));
        accum(hi2f(axu[k]), hi2f(axv[k]), hi2f(ahu[k]), hi2f(ahv[k]), hi2f(atu[k]), hi2f(atv[k]));
    }
    // reduce across the 8 lanes of this edge's group
    RED_GRP(c11) RED_GRP(c12) RED_GRP(c21) RED_GRP(c22)
    RED_GRP(cc12) RED_GRP(cc21) RED_GRP(cc22) RED_GRP(cs12) RED_GRP(cs21)

    if (sub == 0) {
        float* o = out + (size_t)q * 15;
        o[0]  = c11;
        o[1]  = c12;
        o[2]  = c21;
        o[3]  = c22;
        o[4]  = du + dv - 2.f * c11 - c12 - c21;
        o[5]  = du2 + dv2 - 2.f * c22 - c12 - c21;
        o[6]  = cc12;
        o[7]  = cc21;
        o[8]  = cc22;
        o[9]  = cs12;
        o[10] = cs21;
        o[11] = du;
        o[12] = dv;
        o[13] = du2;
        o[14] = dv2;
    }
}

extern "C" void kernel_launch(void* const* d_in, const int* in_sizes, int n_in,
                              void* d_out, int out_size, void* d_ws, size_t ws_size,
                              hipStream_t stream) {
    const float* x       = (const float*)d_in[0];
    const float* w       = (const float*)d_in[1];
    const int*   edges   = (const int*)d_in[2];
    const int*   adj_row = (const int*)d_in[3];
    const int*   adj_col = (const int*)d_in[4];

    const int N    = in_sizes[1];        // node_weight length
    const int E    = in_sizes[2] / 2;
    const int NADJ = in_sizes[3];

    char* ws = (char*)d_ws;
    size_t off = 0;
    auto take = [&](size_t bytes) {
        void* p = ws + off;
        off = (off + bytes + 255) & ~(size_t)255;
        return p;
    };
    uint4*  bundle  = (uint4*)take((size_t)N * BSTRIDE * sizeof(uint4)); // 384 B/node
    float2* degpair = (float2*)take((size_t)N * sizeof(float2));
    int*    row_ptr = (int*)take((size_t)(N + 1) * sizeof(int));
    (void)ws_size;

    float* out = (float*)d_out;

    {   // 1. xw (bf16, into bundle)
        int n8 = N * 8;
        xw_kernel<<<(n8 + 255) / 256, 256, 0, stream>>>((const float4*)x, w, bundle, n8);
    }
    // 2. CSR row pointers from sorted adj_row
    row_ptr_kernel<<<(N + 1 + 255) / 256, 256, 0, stream>>>(adj_row, row_ptr, N, NADJ);
    // 3. one_hop + deg
    spmm_kernel<false><<<(N + 3) / 4, 256, 0, stream>>>(bundle + XW_OFF, row_ptr, adj_col,
                                                        degpair, bundle + H1_OFF, N);
    // 4. two_iter + deg2
    spmm_kernel<true><<<(N + 3) / 4, 256, 0, stream>>>(bundle + H1_OFF, row_ptr, adj_col,
                                                       degpair, bundle + T2_OFF, N);
    // 5. edge features
    edge_kernel<<<((size_t)E * 8 + 255) / 256, 256, 0, stream>>>(edges, bundle, degpair, out, E);
}

// Round 5
// 199.126 us; speedup vs baseline: 2.1506x; 1.0810x over previous
//
#include <hip/hip_runtime.h>

// RandomizedNodeLabeling — bf16 compact tables; spmm = 8 nodes/wave, 8 lanes/node.
// N=100000 nodes, D=64, NADJ=1.6M sorted-row COO, E=262144 query edges.
//
// Node vector = 64 bf16 = 128 B = 8 x uint4 (compact tables, stride 8 uint4).
// Lane sub (0..7) owns dims sub*8..sub*8+7 (lo = even dim of each uint).
//
// spmm: wave = 8 consecutive nodes (group g=lane>>3), lane sub=lane&7 owns 8 dims.
//       Per 8-edge block: 1 coalesced index load, shfl-broadcast within group,
//       8 independent 1 KB gathers in flight; fp32 accumulate per lane;
//       NO reduction epilogue (lane owns its dims); 1 KB contiguous store.
// edge: 8 lanes per edge, 8 edges per wave; 6 independent 128 B gathers per
//       edge, 9 fp32 dots, shfl_xor(1,2,4) reduce.

#define D 64

typedef unsigned int uint32;

__device__ __forceinline__ uint32 pack2(float a, float b) {
    // round-to-nearest-even bf16 pack: a -> lo16, b -> hi16
    uint32 ua = __float_as_uint(a);
    ua += 0x7fffu + ((ua >> 16) & 1u);
    uint32 ub = __float_as_uint(b);
    ub += 0x7fffu + ((ub >> 16) & 1u);
    return (ua >> 16) | (ub & 0xffff0000u);
}
__device__ __forceinline__ float lo2f(uint32 u) { return __uint_as_float(u << 16); }
__device__ __forceinline__ float hi2f(uint32 u) { return __uint_as_float(u & 0xffff0000u); }

#define RED_GRP(v)  { v += __shfl_xor(v, 1, 64); v += __shfl_xor(v, 2, 64);  v += __shfl_xor(v, 4, 64);  }

__global__ void __launch_bounds__(256) xw_kernel(const float4* __restrict__ x,
                                                 const float* __restrict__ w,
                                                 uint4* __restrict__ xw, int n8) {
    int i = blockIdx.x * blockDim.x + threadIdx.x;   // over n*8 uint4 groups
    if (i >= n8) return;
    float s = w[i >> 3];
    float4 a = x[i * 2], b = x[i * 2 + 1];
    uint4 o;
    o.x = pack2(a.x * s, a.y * s);
    o.y = pack2(a.z * s, a.w * s);
    o.z = pack2(b.x * s, b.y * s);
    o.w = pack2(b.z * s, b.w * s);
    xw[i] = o;
}

__global__ void __launch_bounds__(256) row_ptr_kernel(const int* __restrict__ adj_row,
                                                      int* __restrict__ row_ptr,
                                                      int n, int nadj) {
    int i = blockIdx.x * blockDim.x + threadIdx.x;
    if (i > n) return;
    int lo = 0, hi = nadj;                 // lower_bound(adj_row, i)
    while (lo < hi) {
        int mid = (lo + hi) >> 1;
        if (adj_row[mid] < i) lo = mid + 1; else hi = mid;
    }
    row_ptr[i] = lo;
}

// dst = A*src (bf16 compact tables). 8 nodes per wave, 8 lanes per node.
// WITH_DEG2=false: degv[node] = degree
// WITH_DEG2=true : deg2v[node] = max(sum_{nbr} degv[nbr] - deg - 1, 0)
template <bool WITH_DEG2>
__global__ void __launch_bounds__(256) spmm_kernel(const uint4* __restrict__ src,
                                                   const int* __restrict__ row_ptr,
                                                   const int* __restrict__ adj_col,
                                                   const float* __restrict__ degv,
                                                   uint4* __restrict__ dst,
                                                   float* __restrict__ degout,
                                                   int n) {
    int lane = threadIdx.x & 63;
    int g = lane >> 3, sub = lane & 7;
    int node = blockIdx.x * 32 + (threadIdx.x >> 6) * 8 + g;
    if (node >= n) return;
    int start = row_ptr[node], end = row_ptr[node + 1];
    int deg_n = end - start;
    float a0 = 0.f, a1 = 0.f, a2 = 0.f, a3 = 0.f,
          a4 = 0.f, a5 = 0.f, a6 = 0.f, a7 = 0.f;
    float dsum = 0.f;
    int gbase = lane & 56;                 // group's base lane for shfl
    for (int base = 0; base < deg_n; base += 8) {
        int k = base + sub;
        bool kv = k < deg_n;
        int idx = kv ? adj_col[start + k] : 0;   // coalesced 8-per-group
        if (WITH_DEG2) { if (kv) dsum += degv[idx]; }
#pragma unroll
        for (int i = 0; i < 8; ++i) {
            int c = __shfl(idx, gbase + i, 64);  // broadcast group's i-th col
            if (base + i < deg_n) {              // exec-masked tail
                uint4 qv = src[(size_t)c * 8 + sub];
                a0 += lo2f(qv.x); a1 += hi2f(qv.x);
                a2 += lo2f(qv.y); a3 += hi2f(qv.y);
                a4 += lo2f(qv.z); a5 += hi2f(qv.z);
                a6 += lo2f(qv.w); a7 += hi2f(qv.w);
            }
        }
    }
    // lane owns its dims: no reduction; 8 consecutive nodes -> 1 KB contiguous store
    uint4 o;
    o.x = pack2(a0, a1); o.y = pack2(a2, a3);
    o.z = pack2(a4, a5); o.w = pack2(a6, a7);
    dst[(size_t)node * 8 + sub] = o;
    if (WITH_DEG2) {
        RED_GRP(dsum)                      // sum over the group's 8 lanes
        if (sub == 0) degout[node] = fmaxf(dsum - (float)deg_n - 1.0f, 0.0f);
    } else {
        if (sub == 0) degout[node] = (float)deg_n;
    }
}

__global__ void __launch_bounds__(256) edge_kernel(const int* __restrict__ edges, // [2,E]
                                                   const uint4* __restrict__ xw,
                                                   const uint4* __restrict__ h1,
                                                   const uint4* __restrict__ t2,
                                                   const float* __restrict__ deg,
                                                   const float* __restrict__ deg2,
                                                   float* __restrict__ out,
                                                   int E) {
    int t = blockIdx.x * blockDim.x + threadIdx.x;
    int q = t >> 3, sub = t & 7;           // 8 lanes per edge
    if (q >= E) return;
    int u = edges[q], v = edges[E + q];
    uint4 pxu = xw[(size_t)u * 8 + sub], pxv = xw[(size_t)v * 8 + sub];
    uint4 phu = h1[(size_t)u * 8 + sub], phv = h1[(size_t)v * 8 + sub];
    uint4 ptu = t2[(size_t)u * 8 + sub], ptv = t2[(size_t)v * 8 + sub];
    float du = deg[u], dv = deg[v];

    float c11 = 0.f, c12 = 0.f, c21 = 0.f, c22 = 0.f,
          cc12 = 0.f, cc21 = 0.f, cc22 = 0.f, cs12 = 0.f, cs21 = 0.f;

    uint32 axu[4] = {pxu.x, pxu.y, pxu.z, pxu.w};
    uint32 axv[4] = {pxv.x, pxv.y, pxv.z, pxv.w};
    uint32 ahu[4] = {phu.x, phu.y, phu.z, phu.w};
    uint32 ahv[4] = {phv.x, phv.y, phv.z, phv.w};
    uint32 atu[4] = {ptu.x, ptu.y, ptu.z, ptu.w};
    uint32 atv[4] = {ptv.x, ptv.y, ptv.z, ptv.w};

    auto accum = [&](float xu, float xv, float hu, float hv, float tu, float tv) {
        float h2u = tu - hu - xu, h2v = tv - hv - xv;
        float au = fmaf(-du, xu, tu), av = fmaf(-dv, xv, tv);
        c11  = fmaf(hu,  hv,  c11);
        c12  = fmaf(hu,  h2v, c12);
        c21  = fmaf(h2u, hv,  c21);
        c22  = fmaf(h2u, h2v, c22);
        cc12 = fmaf(hu,  tv,  cc12);
        cc21 = fmaf(tu,  hv,  cc21);
        cc22 = fmaf(au,  av,  cc22);
        cs12 = fmaf(hu,  tu,  cs12);
        cs21 = fmaf(hv,  tv,  cs21);
    };
#pragma unroll
    for (int k = 0; k < 4; ++k) {
        accum(lo2f(axu[k]), lo2f(axv[k]), lo2f(ahu[k]), lo2f(ahv[k]), lo2f(atu[k]), lo2f(atv[k]));
        accum(hi2f(axu[k]), hi2f(axv[k]), hi2f(ahu[k]), hi2f(ahv[k]), hi2f(atu[k]), hi2f(atv[k]));
    }
    // reduce across the 8 lanes of this edge's group
    RED_GRP(c11) RED_GRP(c12) RED_GRP(c21) RED_GRP(c22)
    RED_GRP(cc12) RED_GRP(cc21) RED_GRP(cc22) RED_GRP(cs12) RED_GRP(cs21)

    if (sub == 0) {
        float du2 = deg2[u], dv2 = deg2[v];
        float* o = out + (size_t)q * 15;
        o[0]  = c11;
        o[1]  = c12;
        o[2]  = c21;
        o[3]  = c22;
        o[4]  = du + dv - 2.f * c11 - c12 - c21;
        o[5]  = du2 + dv2 - 2.f * c22 - c12 - c21;
        o[6]  = cc12;
        o[7]  = cc21;
        o[8]  = cc22;
        o[9]  = cs12;
        o[10] = cs21;
        o[11] = du;
        o[12] = dv;
        o[13] = du2;
        o[14] = dv2;
    }
}

extern "C" void kernel_launch(void* const* d_in, const int* in_sizes, int n_in,
                              void* d_out, int out_size, void* d_ws, size_t ws_size,
                              hipStream_t stream) {
    const float* x       = (const float*)d_in[0];
    const float* w       = (const float*)d_in[1];
    const int*   edges   = (const int*)d_in[2];
    const int*   adj_row = (const int*)d_in[3];
    const int*   adj_col = (const int*)d_in[4];

    const int N    = in_sizes[1];        // node_weight length
    const int E    = in_sizes[2] / 2;
    const int NADJ = in_sizes[3];

    char* ws = (char*)d_ws;
    size_t off = 0;
    auto take = [&](size_t bytes) {
        void* p = ws + off;
        off = (off + bytes + 255) & ~(size_t)255;
        return p;
    };
    uint4* xw      = (uint4*)take((size_t)N * D * 2);   // bf16 tables, 128 B/node
    uint4* one_hop = (uint4*)take((size_t)N * D * 2);
    uint4* two_it  = (uint4*)take((size_t)N * D * 2);
    float* deg     = (float*)take((size_t)N * sizeof(float));
    float* deg2    = (float*)take((size_t)N * sizeof(float));
    int*   row_ptr = (int*)take((size_t)(N + 1) * sizeof(int));
    (void)ws_size;

    float* out = (float*)d_out;

    {   // 1. xw (bf16)
        int n8 = N * 8;
        xw_kernel<<<(n8 + 255) / 256, 256, 0, stream>>>((const float4*)x, w, xw, n8);
    }
    // 2. CSR row pointers from sorted adj_row
    row_ptr_kernel<<<(N + 1 + 255) / 256, 256, 0, stream>>>(adj_row, row_ptr, N, NADJ);
    // 3. one_hop + deg   (32 nodes per 256-thread block)
    spmm_kernel<false><<<(N + 31) / 32, 256, 0, stream>>>(xw, row_ptr, adj_col, nullptr,
                                                          one_hop, deg, N);
    // 4. two_iter + deg2
    spmm_kernel<true><<<(N + 31) / 32, 256, 0, stream>>>(one_hop, row_ptr, adj_col, deg,
                                                         two_it, deg2, N);
    // 5. edge features
    edge_kernel<<<((size_t)E * 8 + 255) / 256, 256, 0, stream>>>(edges, xw, one_hop, two_it,
                                                                 deg, deg2, out, E);
}

// Round 6
// 188.882 us; speedup vs baseline: 2.2672x; 1.0542x over previous
//
#include <hip/hip_runtime.h>

// RandomizedNodeLabeling — bf16 compact tables; spmm = 8 nodes/wave, 8 lanes/node.
// N=100000 nodes, D=64, NADJ=1.6M sorted-row COO, E=262144 query edges.
//
// Node vector = 64 bf16 = 128 B = 8 x uint4 (compact tables, stride 8 uint4).
// Lane sub (0..7) owns dims sub*8..sub*8+7 (lo = even dim of each uint).
//
// Dispatches (4): prep(xw | row_ptr) -> spmm1 -> spmm2 -> edge.
// spmm: wave = 8 consecutive nodes; per 8-edge block one coalesced index load,
//       shfl broadcast, 8 independent 1 KB gathers; full blocks run maskless,
//       only the tail block pays per-iter exec masks. No reduction epilogue.
// edge: 8 lanes per edge; 6 independent 128 B gathers + 1 float2 degpair per
//       endpoint, 9 fp32 dots, shfl_xor(1,2,4) reduce.

#define D 64

typedef unsigned int uint32;

__device__ __forceinline__ uint32 pack2(float a, float b) {
    // round-to-nearest-even bf16 pack: a -> lo16, b -> hi16
    uint32 ua = __float_as_uint(a);
    ua += 0x7fffu + ((ua >> 16) & 1u);
    uint32 ub = __float_as_uint(b);
    ub += 0x7fffu + ((ub >> 16) & 1u);
    return (ua >> 16) | (ub & 0xffff0000u);
}
__device__ __forceinline__ float lo2f(uint32 u) { return __uint_as_float(u << 16); }
__device__ __forceinline__ float hi2f(uint32 u) { return __uint_as_float(u & 0xffff0000u); }

#define RED_GRP(v)  { v += __shfl_xor(v, 1, 64); v += __shfl_xor(v, 2, 64);  v += __shfl_xor(v, 4, 64);  }

// blocks [0, xw_blocks): xw = x*w packed to bf16.  blocks [xw_blocks, ...): row_ptr.
__global__ void __launch_bounds__(256) prep_kernel(const float4* __restrict__ x,
                                                   const float* __restrict__ w,
                                                   uint4* __restrict__ xw,
                                                   const int* __restrict__ adj_row,
                                                   int* __restrict__ row_ptr,
                                                   int n8, int n, int nadj, int xw_blocks) {
    if ((int)blockIdx.x < xw_blocks) {
        int i = blockIdx.x * blockDim.x + threadIdx.x;   // over n*8 uint4 groups
        if (i >= n8) return;
        float s = w[i >> 3];
        float4 a = x[i * 2], b = x[i * 2 + 1];
        uint4 o;
        o.x = pack2(a.x * s, a.y * s);
        o.y = pack2(a.z * s, a.w * s);
        o.z = pack2(b.x * s, b.y * s);
        o.w = pack2(b.z * s, b.w * s);
        xw[i] = o;
    } else {
        int i = (blockIdx.x - xw_blocks) * blockDim.x + threadIdx.x;
        if (i > n) return;
        int lo = 0, hi = nadj;                 // lower_bound(adj_row, i)
        while (lo < hi) {
            int mid = (lo + hi) >> 1;
            if (adj_row[mid] < i) lo = mid + 1; else hi = mid;
        }
        row_ptr[i] = lo;
    }
}

// dst = A*src (bf16 compact tables). 8 nodes per wave, 8 lanes per node.
// WITH_DEG2=false: degout[node] = degree
// WITH_DEG2=true : degpair[node] = {deg, max(sum_{nbr} degv[nbr] - deg - 1, 0)}
template <bool WITH_DEG2>
__global__ void __launch_bounds__(256) spmm_kernel(const uint4* __restrict__ src,
                                                   const int* __restrict__ row_ptr,
                                                   const int* __restrict__ adj_col,
                                                   const float* __restrict__ degv,
                                                   uint4* __restrict__ dst,
                                                   float* __restrict__ degout,
                                                   float2* __restrict__ degpair,
                                                   int n) {
    int lane = threadIdx.x & 63;
    int sub = lane & 7;
    int node = blockIdx.x * 32 + (threadIdx.x >> 6) * 8 + (lane >> 3);
    if (node >= n) return;
    int start = row_ptr[node], end = row_ptr[node + 1];
    int deg_n = end - start;
    float a0 = 0.f, a1 = 0.f, a2 = 0.f, a3 = 0.f,
          a4 = 0.f, a5 = 0.f, a6 = 0.f, a7 = 0.f;
    float dsum = 0.f;
    int gbase = lane & 56;                 // group's base lane for shfl
    const int* colp = adj_col + start;
    int base = 0;
    // full 8-edge blocks: trip condition is group-uniform -> maskless body
    for (; base + 8 <= deg_n; base += 8) {
        int idx = colp[base + sub];        // coalesced 8-per-group
        if (WITH_DEG2) dsum += degv[idx];
#pragma unroll
        for (int i = 0; i < 8; ++i) {
            int c = __shfl(idx, gbase + i, 64);
            uint4 qv = src[(size_t)c * 8 + sub];
            a0 += lo2f(qv.x); a1 += hi2f(qv.x);
            a2 += lo2f(qv.y); a3 += hi2f(qv.y);
            a4 += lo2f(qv.z); a5 += hi2f(qv.z);
            a6 += lo2f(qv.w); a7 += hi2f(qv.w);
        }
    }
    if (base < deg_n) {                    // tail block, exec-masked
        int k = base + sub;
        bool kv = k < deg_n;
        int idx = kv ? colp[k] : 0;
        if (WITH_DEG2) { if (kv) dsum += degv[idx]; }
#pragma unroll
        for (int i = 0; i < 8; ++i) {
            if (base + i < deg_n) {        // group-uniform predicate
                int c = __shfl(idx, gbase + i, 64);
                uint4 qv = src[(size_t)c * 8 + sub];
                a0 += lo2f(qv.x); a1 += hi2f(qv.x);
                a2 += lo2f(qv.y); a3 += hi2f(qv.y);
                a4 += lo2f(qv.z); a5 += hi2f(qv.z);
                a6 += lo2f(qv.w); a7 += hi2f(qv.w);
            }
        }
    }
    // lane owns its dims: no reduction; 8 consecutive nodes -> 1 KB contiguous store
    uint4 o;
    o.x = pack2(a0, a1); o.y = pack2(a2, a3);
    o.z = pack2(a4, a5); o.w = pack2(a6, a7);
    dst[(size_t)node * 8 + sub] = o;
    if (WITH_DEG2) {
        RED_GRP(dsum)                      // sum over the group's 8 lanes
        if (sub == 0)
            degpair[node] = make_float2((float)deg_n,
                                        fmaxf(dsum - (float)deg_n - 1.0f, 0.0f));
    } else {
        if (sub == 0) degout[node] = (float)deg_n;
    }
}

__global__ void __launch_bounds__(256) edge_kernel(const int* __restrict__ edges, // [2,E]
                                                   const uint4* __restrict__ xw,
                                                   const uint4* __restrict__ h1,
                                                   const uint4* __restrict__ t2,
                                                   const float2* __restrict__ degpair,
                                                   float* __restrict__ out,
                                                   int E) {
    int t = blockIdx.x * blockDim.x + threadIdx.x;
    int q = t >> 3, sub = t & 7;           // 8 lanes per edge
    if (q >= E) return;
    int u = edges[q], v = edges[E + q];
    uint4 pxu = xw[(size_t)u * 8 + sub], pxv = xw[(size_t)v * 8 + sub];
    uint4 phu = h1[(size_t)u * 8 + sub], phv = h1[(size_t)v * 8 + sub];
    uint4 ptu = t2[(size_t)u * 8 + sub], ptv = t2[(size_t)v * 8 + sub];
    float2 dpu = degpair[u], dpv = degpair[v];
    float du = dpu.x, du2 = dpu.y, dv = dpv.x, dv2 = dpv.y;

    float c11 = 0.f, c12 = 0.f, c21 = 0.f, c22 = 0.f,
          cc12 = 0.f, cc21 = 0.f, cc22 = 0.f, cs12 = 0.f, cs21 = 0.f;

    uint32 axu[4] = {pxu.x, pxu.y, pxu.z, pxu.w};
    uint32 axv[4] = {pxv.x, pxv.y, pxv.z, pxv.w};
    uint32 ahu[4] = {phu.x, phu.y, phu.z, phu.w};
    uint32 ahv[4] = {phv.x, phv.y, phv.z, phv.w};
    uint32 atu[4] = {ptu.x, ptu.y, ptu.z, ptu.w};
    uint32 atv[4] = {ptv.x, ptv.y, ptv.z, ptv.w};

    auto accum = [&](float xu, float xv, float hu, float hv, float tu, float tv) {
        float h2u = tu - hu - xu, h2v = tv - hv - xv;
        float au = fmaf(-du, xu, tu), av = fmaf(-dv, xv, tv);
        c11  = fmaf(hu,  hv,  c11);
        c12  = fmaf(hu,  h2v, c12);
        c21  = fmaf(h2u, hv,  c21);
        c22  = fmaf(h2u, h2v, c22);
        cc12 = fmaf(hu,  tv,  cc12);
        cc21 = fmaf(tu,  hv,  cc21);
        cc22 = fmaf(au,  av,  cc22);
        cs12 = fmaf(hu,  tu,  cs12);
        cs21 = fmaf(hv,  tv,  cs21);
    };
#pragma unroll
    for (int k = 0; k < 4; ++k) {
        accum(lo2f(axu[k]), lo2f(axv[k]), lo2f(ahu[k]), lo2f(ahv[k]), lo2f(atu[k]), lo2f(atv[k]));
        accum(hi2f(axu[k]), hi2f(axv[k]), hi2f(ahu[k]), hi2f(ahv[k]), hi2f(atu[k]), hi2f(atv[k]));
    }
    // reduce across the 8 lanes of this edge's group
    RED_GRP(c11) RED_GRP(c12) RED_GRP(c21) RED_GRP(c22)
    RED_GRP(cc12) RED_GRP(cc21) RED_GRP(cc22) RED_GRP(cs12) RED_GRP(cs21)

    if (sub == 0) {
        float* o = out + (size_t)q * 15;
        o[0]  = c11;
        o[1]  = c12;
        o[2]  = c21;
        o[3]  = c22;
        o[4]  = du + dv - 2.f * c11 - c12 - c21;
        o[5]  = du2 + dv2 - 2.f * c22 - c12 - c21;
        o[6]  = cc12;
        o[7]  = cc21;
        o[8]  = cc22;
        o[9]  = cs12;
        o[10] = cs21;
        o[11] = du;
        o[12] = dv;
        o[13] = du2;
        o[14] = dv2;
    }
}

extern "C" void kernel_launch(void* const* d_in, const int* in_sizes, int n_in,
                              void* d_out, int out_size, void* d_ws, size_t ws_size,
                              hipStream_t stream) {
    const float* x       = (const float*)d_in[0];
    const float* w       = (const float*)d_in[1];
    const int*   edges   = (const int*)d_in[2];
    const int*   adj_row = (const int*)d_in[3];
    const int*   adj_col = (const int*)d_in[4];

    const int N    = in_sizes[1];        // node_weight length
    const int E    = in_sizes[2] / 2;
    const int NADJ = in_sizes[3];

    char* ws = (char*)d_ws;
    size_t off = 0;
    auto take = [&](size_t bytes) {
        void* p = ws + off;
        off = (off + bytes + 255) & ~(size_t)255;
        return p;
    };
    uint4*  xw      = (uint4*)take((size_t)N * D * 2);   // bf16 tables, 128 B/node
    uint4*  one_hop = (uint4*)take((size_t)N * D * 2);
    uint4*  two_it  = (uint4*)take((size_t)N * D * 2);
    float*  deg     = (float*)take((size_t)N * sizeof(float));
    float2* degpair = (float2*)take((size_t)N * sizeof(float2));
    int*    row_ptr = (int*)take((size_t)(N + 1) * sizeof(int));
    (void)ws_size;

    float* out = (float*)d_out;

    // 1. fused: xw (bf16) + CSR row pointers
    {
        int n8 = N * 8;
        int xw_blocks = (n8 + 255) / 256;
        int rp_blocks = (N + 1 + 255) / 256;
        prep_kernel<<<xw_blocks + rp_blocks, 256, 0, stream>>>(
            (const float4*)x, w, xw, adj_row, row_ptr, n8, N, NADJ, xw_blocks);
    }
    // 2. one_hop + deg   (32 nodes per 256-thread block)
    spmm_kernel<false><<<(N + 31) / 32, 256, 0, stream>>>(xw, row_ptr, adj_col, nullptr,
                                                          one_hop, deg, nullptr, N);
    // 3. two_iter + degpair{deg,deg2}
    spmm_kernel<true><<<(N + 31) / 32, 256, 0, stream>>>(one_hop, row_ptr, adj_col, deg,
                                                         two_it, nullptr, degpair, N);
    // 4. edge features
    edge_kernel<<<((size_t)E * 8 + 255) / 256, 256, 0, stream>>>(edges, xw, one_hop, two_it,
                                                                 degpair, out, E);
}